// Round 18
// baseline (538.748 us; speedup 1.0000x reference)
//
#include <hip/hip_runtime.h>
#include <stdint.h>

// B=8, OBJ=128, INP=64, HID=256, D=192.
// R18: SINGLE kernel with a SOFTWARE grid barrier (cooperative launch failed
// in this harness). Grid 512 x launch_bounds(256,2) x 64KB LDS = exactly
// 2 blocks/CU x 256 CUs -> all blocks co-resident, spin barrier can't
// deadlock. Barrier = per-block MAGIC flags (poison-proof: ws re-poisoned
// 0xAA before every launch), device-scope atomics + threadfence for
// cross-XCD visibility. Phase 0: encoder + w1/w2 frag-pack + W34=w3@wd1
// fold. Phase 1: two R16 pair-units per block (2 MFMA layers + fused dec).

#define HID 256
#define NOBJ 128
#define NROW 1024   // B*OBJ
#define MAGIC 0x13572468u

typedef __attribute__((ext_vector_type(8))) short short8;
typedef __attribute__((ext_vector_type(4))) float float4v;
typedef __attribute__((ext_vector_type(16))) float float16v;
typedef __attribute__((ext_vector_type(2))) unsigned int uint2v;

__device__ __forceinline__ unsigned int f2bf_u(float f) {
    unsigned int u = __builtin_bit_cast(unsigned int, f);
    u += 0x7fffu + ((u >> 16) & 1u);   // RNE
    return u >> 16;
}
__device__ __forceinline__ unsigned int pack2(float a, float b) {
    return f2bf_u(a) | (f2bf_u(b) << 16);
}
__device__ __forceinline__ float relu(float v) { return v > 0.f ? v : 0.f; }

__device__ __forceinline__ void lds_barrier() {
    asm volatile("s_waitcnt lgkmcnt(0)\n\ts_barrier" ::: "memory");
}

__global__ __launch_bounds__(256, 2) void fused_kernel(
        const float* __restrict__ x0, const float* __restrict__ x1,
        const float* __restrict__ x2, const float* __restrict__ w_enc,
        const float* __restrict__ b_enc,
        const float* __restrict__ w1, const float* __restrict__ b1,
        const float* __restrict__ w2, const float* __restrict__ b2,
        const float* __restrict__ w3, const float* __restrict__ b3,
        const float* __restrict__ wd1, const float* __restrict__ bd1,
        const float* __restrict__ wd2, const float* __restrict__ bd2,
        unsigned short* __restrict__ wt, float* __restrict__ ea,
        float* __restrict__ eb, float* __restrict__ W34,
        float* __restrict__ b34, unsigned int* __restrict__ flags,
        float* __restrict__ out) {
    __shared__ __align__(16) unsigned short hbuf[128 * 256];   // 64 KB

    const int bx = blockIdx.x, t = threadIdx.x;
    const int lane = t & 63, wv = t >> 6;
    const int l31 = lane & 31, h5 = lane >> 5;

    // ================= phase 0: setup =================
    {
        // encoder: block bx handles rows bx*2, bx*2+1 (fold b_enc into ea)
        float* xs = (float*)hbuf;                     // [2][192]
        for (int idx = t; idx < 384; idx += 256) {
            int r = idx / 192, d = idx % 192;
            int row = bx * 2 + r;
            float v = (d < 64) ? x0[row * 64 + d]
                    : (d < 128) ? x1[row * 64 + d - 64]
                    : x2[row * 64 + d - 128];
            xs[r * 192 + d] = v;
        }
        __syncthreads();
        float aA[2] = {0.f, 0.f}, aB[2] = {0.f, 0.f};
#pragma unroll 16
        for (int d = 0; d < 192; ++d) {
            float wa = w_enc[d * 256 + t];
            float wb = w_enc[(192 + d) * 256 + t];
#pragma unroll
            for (int r = 0; r < 2; ++r) {
                aA[r] += xs[r * 192 + d] * wa;
                aB[r] += xs[r * 192 + d] * wb;
            }
        }
        float be = b_enc[t];
#pragma unroll
        for (int r = 0; r < 2; ++r) {
            ea[(bx * 2 + r) * 256 + t] = aA[r] + be;
            eb[(bx * 2 + r) * 256 + t] = aB[r];
        }
        __syncthreads();

        if (bx < 16) {
            // fragment-major pack of w1/w2: layer m = bx>>3, n-tile tau = bx&7
            const int m = bx >> 3, tau = bx & 7;
            const float* w = (m == 0) ? w1 : w2;
            float* lw = (float*)hbuf;                 // [256][33]
            const int n = t & 31, kk = t >> 5;
#pragma unroll
            for (int rep = 0; rep < 32; ++rep) {
                int k = rep * 8 + kk;
                lw[k * 33 + n] = w[k * 256 + tau * 32 + n];
            }
            __syncthreads();
            unsigned short* outp = wt + (m * 8 + tau) * 8192;
#pragma unroll
            for (int rep = 0; rep < 4; ++rep) {
                const int kb = wv * 4 + rep;
                short8 v;
#pragma unroll
                for (int e = 0; e < 8; ++e)
                    v[e] = (short)f2bf_u(lw[(kb * 16 + h5 * 8 + e) * 33 + l31]);
                *(short8*)(outp + kb * 512 + lane * 8) = v;
            }
        } else if (bx < 272) {
            const int m = bx - 16;                    // W34 row
            float a = 0.f;
#pragma unroll 8
            for (int k = 0; k < 256; ++k) a += w3[m * 256 + k] * wd1[k * 256 + t];
            W34[m * 256 + t] = a;
        } else if (bx == 272) {
            float a = bd1[t];
#pragma unroll 8
            for (int k = 0; k < 256; ++k) a += b3[k] * wd1[k * 256 + t];
            b34[t] = a;
        }
    }

    // ================= software grid barrier =================
    // All 512 blocks are co-resident (2/CU x 256 CU). flags[] starts poisoned
    // (0xAAAAAAAA != MAGIC) — re-poisoned by the harness before every launch.
    __syncthreads();
    __threadfence();                                  // release: phase-0 stores visible
    if (t == 0)
        __hip_atomic_store(&flags[bx], MAGIC, __ATOMIC_RELEASE, __HIP_MEMORY_SCOPE_AGENT);
    // thread t spins on flags[t] and flags[t+256]
    while (__hip_atomic_load(&flags[t], __ATOMIC_ACQUIRE, __HIP_MEMORY_SCOPE_AGENT) != MAGIC) {}
    while (__hip_atomic_load(&flags[t + 256], __ATOMIC_ACQUIRE, __HIP_MEMORY_SCOPE_AGENT) != MAGIC) {}
    __threadfence();                                  // acquire: invalidate stale caches
    __syncthreads();

    // ================= phase 1: two pair-units per block =================
    for (int rep = 0; rep < 2; ++rep) {
        const int w = bx + rep * 512, b = w >> 7;
        const int n0 = wv * 64;
        const unsigned short* aptr = wt + lane * 8;

        short8 af[2][2], bfr[2][4];
        af[0][0] = *(const short8*)(aptr + ((wv * 2 + 0) * 16) * 512);
        af[0][1] = *(const short8*)(aptr + ((wv * 2 + 1) * 16) * 512);

        // preamble: h0[j][k] = relu(ea[w][k] + eb[b*128+j][k]); wave fills j=wv*32..+31
        {
            const float4v va = *(const float4v*)(ea + w * 256 + lane * 4);
            const float* ebbase = eb + (b * NOBJ) * 256;
            const int c = lane >> 1, sub = (lane & 1) * 4;
#pragma unroll 4
            for (int jj = 0; jj < 32; ++jj) {
                const int j = wv * 32 + jj;
                float4v vb = *(const float4v*)(ebbase + j * 256 + lane * 4);
                int addr = j * 256 + ((c ^ (j & 31)) << 3) + sub;
                *(uint2v*)(hbuf + addr) = (uint2v){
                    pack2(relu(va[0] + vb[0]), relu(va[1] + vb[1])),
                    pack2(relu(va[2] + vb[2]), relu(va[3] + vb[3]))};
            }
        }
        lds_barrier();

        int jb[4];
#pragma unroll
        for (int tj = 0; tj < 4; ++tj) jb[tj] = (tj * 32 + l31) * 256;
#pragma unroll
        for (int tj = 0; tj < 4; ++tj)
            bfr[0][tj] = *(const short8*)(hbuf + jb[tj] + ((h5 ^ l31) << 3));

        float16v acc[2][4];   // [tn][tj]

#pragma unroll
        for (int l = 0; l < 2; ++l) {
            const float* bias = (l == 0) ? b1 : b2;
#pragma unroll
            for (int tn = 0; tn < 2; ++tn)
#pragma unroll
                for (int q = 0; q < 4; ++q) {
                    float4v bv = *(const float4v*)(bias + n0 + tn * 32 + q * 8 + h5 * 4);
#pragma unroll
                    for (int i = 0; i < 4; ++i)
#pragma unroll
                        for (int tj = 0; tj < 4; ++tj)
                            acc[tn][tj][q * 4 + i] = bv[i];
                }
#pragma unroll
            for (int kb = 0; kb < 16; ++kb) {
                const int g = l * 16 + kb, gp = g + 1;
                if (gp < 32) {
                    const int lp = gp >> 4, kp = gp & 15;
                    af[gp & 1][0] = *(const short8*)(aptr + ((lp * 8 + wv * 2 + 0) * 16 + kp) * 512);
                    af[gp & 1][1] = *(const short8*)(aptr + ((lp * 8 + wv * 2 + 1) * 16 + kp) * 512);
                }
                if (kb < 15) {
                    const int off = ((((kb + 1) * 2 + h5) ^ l31) << 3);
#pragma unroll
                    for (int tj = 0; tj < 4; ++tj)
                        bfr[(kb + 1) & 1][tj] = *(const short8*)(hbuf + jb[tj] + off);
                }
#pragma unroll
                for (int tn = 0; tn < 2; ++tn)
#pragma unroll
                    for (int tj = 0; tj < 4; ++tj)
                        acc[tn][tj] = __builtin_amdgcn_mfma_f32_32x32x16_bf16(
                            af[g & 1][tn], bfr[kb & 1][tj], acc[tn][tj], 0, 0, 0);
            }
            lds_barrier();

            if (l == 0) {
                // writeback h1 (relu, bf16) into swizzled layout
#pragma unroll
                for (int tn = 0; tn < 2; ++tn)
#pragma unroll
                    for (int q = 0; q < 4; ++q) {
                        const int nb_ = n0 + tn * 32 + 8 * q + 4 * h5;
                        const int cn = nb_ >> 3, sub = nb_ & 7;
#pragma unroll
                        for (int tj = 0; tj < 4; ++tj) {
                            const int j = tj * 32 + l31;
                            int addr = j * 256 + ((cn ^ l31) << 3) + sub;
                            *(uint2v*)(hbuf + addr) = (uint2v){
                                pack2(relu(acc[tn][tj][q * 4]), relu(acc[tn][tj][q * 4 + 1])),
                                pack2(relu(acc[tn][tj][q * 4 + 2]), relu(acc[tn][tj][q * 4 + 3]))};
                        }
                    }
                lds_barrier();
#pragma unroll
                for (int tj = 0; tj < 4; ++tj)
                    bfr[0][tj] = *(const short8*)(hbuf + jb[tj] + ((h5 ^ l31) << 3));
            }
        }

        // epilogue: m2 = mean_j relu(acc); t1 = relu(m2@W34 + b34); out = t1@wd2 + bd2
        float* fs = (float*)hbuf;   // m2[0..256) | p1[256..1280) | t1[1280..1536) | p2[1536..1792)
        {
#pragma unroll
            for (int tn = 0; tn < 2; ++tn)
#pragma unroll
                for (int r = 0; r < 16; ++r) {
                    float s = relu(acc[tn][0][r]) + relu(acc[tn][1][r])
                            + relu(acc[tn][2][r]) + relu(acc[tn][3][r]);
                    s += __shfl_xor(s, 1);
                    s += __shfl_xor(s, 2);
                    s += __shfl_xor(s, 4);
                    s += __shfl_xor(s, 8);
                    s += __shfl_xor(s, 16);
                    if (l31 == 0) {
                        const int n = n0 + tn * 32 + (r & 3) + 8 * (r >> 2) + 4 * h5;
                        fs[n] = s * 0.0078125f;
                    }
                }
        }
        __syncthreads();
        {   // stage 1: m2 @ W34, 4-way k-split (wave wv covers k in [wv*64, +64))
            float p0 = 0.f, p1 = 0.f, p2 = 0.f, p3 = 0.f;
            const float* wp = W34 + (wv * 64) * 256 + lane;
#pragma unroll 8
            for (int kk = 0; kk < 64; ++kk) {
                float mv = fs[wv * 64 + kk];
                p0 += mv * wp[kk * 256];
                p1 += mv * wp[kk * 256 + 64];
                p2 += mv * wp[kk * 256 + 128];
                p3 += mv * wp[kk * 256 + 192];
            }
            fs[256 + wv * 256 + lane]       = p0;
            fs[256 + wv * 256 + 64 + lane]  = p1;
            fs[256 + wv * 256 + 128 + lane] = p2;
            fs[256 + wv * 256 + 192 + lane] = p3;
        }
        __syncthreads();
        fs[1280 + t] = relu(fs[256 + t] + fs[512 + t] + fs[768 + t] + fs[1024 + t] + b34[t]);
        __syncthreads();
        {   // stage 2: t1 @ wd2 (wave wv covers k in [wv*64, +64), lane = output o)
            float p = 0.f;
            const float* w2p = wd2 + (wv * 64) * 64 + lane;
#pragma unroll 8
            for (int kk = 0; kk < 64; ++kk) p += fs[1280 + wv * 64 + kk] * w2p[kk * 64];
            fs[1536 + wv * 64 + lane] = p;
        }
        __syncthreads();
        if (t < 64)
            out[w * 64 + t] = fs[1536 + t] + fs[1600 + t] + fs[1664 + t] + fs[1728 + t] + bd2[t];
        __syncthreads();   // fs reads done before next rep's preamble writes hbuf
    }
}

extern "C" void kernel_launch(void* const* d_in, const int* in_sizes, int n_in,
                              void* d_out, int out_size, void* d_ws, size_t ws_size,
                              hipStream_t stream) {
    const float* x0    = (const float*)d_in[0];
    const float* x1    = (const float*)d_in[1];
    const float* x2    = (const float*)d_in[2];
    const float* w_enc = (const float*)d_in[3];
    const float* b_enc = (const float*)d_in[4];
    const float* w1    = (const float*)d_in[5];
    const float* b1    = (const float*)d_in[6];
    const float* w2    = (const float*)d_in[7];
    const float* b2    = (const float*)d_in[8];
    const float* w3    = (const float*)d_in[9];
    const float* b3    = (const float*)d_in[10];
    const float* wd1   = (const float*)d_in[11];
    const float* bd1   = (const float*)d_in[12];
    const float* wd2   = (const float*)d_in[13];
    const float* bd2   = (const float*)d_in[14];
    float* out = (float*)d_out;

    // workspace: wfrag 256KB (384KB slot) | ea 1MB | eb 1MB | W34 256KB | b34 1KB | flags 2KB
    unsigned short* wt = (unsigned short*)d_ws;
    float* ea  = (float*)((char*)d_ws + 3 * 65536 * sizeof(unsigned short));
    float* eb  = ea + NROW * HID;
    float* W34 = eb + NROW * HID;
    float* b34 = W34 + 256 * 256;
    unsigned int* flags = (unsigned int*)(b34 + 256);

    fused_kernel<<<512, 256, 0, stream>>>(x0, x1, x2, w_enc, b_enc,
                                          w1, b1, w2, b2, w3, b3,
                                          wd1, bd1, wd2, bd2,
                                          wt, ea, eb, W34, b34, flags, out);
}

// Round 19
// 161.498 us; speedup vs baseline: 3.3359x; 3.3359x over previous
//
#include <hip/hip_runtime.h>
#include <stdint.h>

// B=8, OBJ=128, INP=64, HID=256, D=192.
// R19 = R16 (best stable: 154.3us) with a leaner fused-decoder epilogue:
// stage-1 GEMV is now a direct per-thread 256-k dot (coalesced W34 loads),
// removing the 4-way-split partial stores (1KB LDS), the combine pass, and
// one __syncthreads. R17/R18 established single-launch fusion is not viable
// in this harness (coop launch fails; spin barrier costs ~400us in cache
// invalidation traffic) — two launches is the floor structure.

#define HID 256
#define NOBJ 128
#define NROW 1024   // B*OBJ

typedef __attribute__((ext_vector_type(8))) short short8;
typedef __attribute__((ext_vector_type(4))) float float4v;
typedef __attribute__((ext_vector_type(16))) float float16v;
typedef __attribute__((ext_vector_type(2))) unsigned int uint2v;

__device__ __forceinline__ unsigned int f2bf_u(float f) {
    unsigned int u = __builtin_bit_cast(unsigned int, f);
    u += 0x7fffu + ((u >> 16) & 1u);   // RNE
    return u >> 16;
}
__device__ __forceinline__ unsigned int pack2(float a, float b) {
    return f2bf_u(a) | (f2bf_u(b) << 16);
}
__device__ __forceinline__ float relu(float v) { return v > 0.f ? v : 0.f; }

// LDS-only barrier: leaves global-load (vmcnt) prefetches in flight.
__device__ __forceinline__ void lds_barrier() {
    asm volatile("s_waitcnt lgkmcnt(0)\n\ts_barrier" ::: "memory");
}

// ---- setup:
//  blocks [0,16): fragment-major pack of w1,w2 (layer m = bx>>3, n-tile tau = bx&7)
//  blocks [16,528): encoder, 2 rows each (fold b_enc into ea)
//  blocks [528,784): W34 row m = bx-528:  W34[m][o] = sum_k w3[m][k]*wd1[k][o]
//  block  784:       b34[o] = sum_k b3[k]*wd1[k][o] + bd1[o]
__global__ void setup_kernel(const float* __restrict__ x0, const float* __restrict__ x1,
                             const float* __restrict__ x2, const float* __restrict__ w_enc,
                             const float* __restrict__ b_enc,
                             const float* __restrict__ w1, const float* __restrict__ w2,
                             const float* __restrict__ w3, const float* __restrict__ b3,
                             const float* __restrict__ wd1, const float* __restrict__ bd1,
                             unsigned short* __restrict__ wt,
                             float* __restrict__ ea, float* __restrict__ eb,
                             float* __restrict__ W34, float* __restrict__ b34) {
    const int bx = blockIdx.x, t = threadIdx.x;
    __shared__ float lw[256][33];          // [k][n-within-tile]
    __shared__ float xs[2][192];
    if (bx < 16) {
        const int m = bx >> 3, tau = bx & 7;
        const float* w = (m == 0) ? w1 : w2;
        const int n = t & 31, kk = t >> 5;     // 8 k-rows per pass
#pragma unroll
        for (int rep = 0; rep < 32; ++rep) {
            int k = rep * 8 + kk;
            lw[k][n] = w[k * 256 + tau * 32 + n];   // coalesced 128B segments
        }
        __syncthreads();
        unsigned short* outp = wt + (m * 8 + tau) * 8192;
        const int lane = t & 63, wq = t >> 6;
        const int h5 = lane >> 5, l31n = lane & 31;
#pragma unroll
        for (int rep = 0; rep < 4; ++rep) {
            const int kb = wq * 4 + rep;
            short8 v;
#pragma unroll
            for (int e = 0; e < 8; ++e)
                v[e] = (short)f2bf_u(lw[kb * 16 + h5 * 8 + e][l31n]);
            *(short8*)(outp + kb * 512 + lane * 8) = v;   // wave-contiguous 1KB
        }
        return;
    }
    if (bx < 528) {
        const int e = bx - 16;                 // 512 groups x 2 rows
        for (int idx = t; idx < 384; idx += 256) {
            int r = idx / 192, d = idx % 192;
            int row = e * 2 + r;
            float v = (d < 64) ? x0[row * 64 + d]
                    : (d < 128) ? x1[row * 64 + d - 64]
                    : x2[row * 64 + d - 128];
            xs[r][d] = v;
        }
        __syncthreads();
        float aA[2] = {0.f, 0.f}, aB[2] = {0.f, 0.f};
#pragma unroll 16
        for (int d = 0; d < 192; ++d) {
            float wa = w_enc[d * 256 + t];
            float wb = w_enc[(192 + d) * 256 + t];
#pragma unroll
            for (int r = 0; r < 2; ++r) { aA[r] += xs[r][d] * wa; aB[r] += xs[r][d] * wb; }
        }
        float be = b_enc[t];
#pragma unroll
        for (int r = 0; r < 2; ++r) {
            ea[(e * 2 + r) * 256 + t] = aA[r] + be;
            eb[(e * 2 + r) * 256 + t] = aB[r];
        }
        return;
    }
    if (bx < 784) {
        const int m = bx - 528;
        float a = 0.f;
#pragma unroll 8
        for (int k = 0; k < 256; ++k) a += w3[m * 256 + k] * wd1[k * 256 + t];
        W34[m * 256 + t] = a;
        return;
    }
    {   // b34
        float a = bd1[t];
#pragma unroll 8
        for (int k = 0; k < 256; ++k) a += b3[k] * wd1[k * 256 + t];
        b34[t] = a;
    }
}

// ---- pair MLP (2 layers) + fused decoder: grid 1024, one WG per (b,i).
//      128 j-rows, 64 KB LDS h, swizzle: elem(j,k) at
//      j*256 + ((k>>3 ^ (j&31))<<3) + (k&7). Wave wv owns n-quarter n0=wv*64
//      as tn=2 x tj=4 tiles of 32x32x16. af ring-2 (distance 1).
__global__ __launch_bounds__(256, 2) void pair_kernel(
        const float* __restrict__ ea, const float* __restrict__ eb,
        const unsigned short* __restrict__ wt,
        const float* __restrict__ b1, const float* __restrict__ b2,
        const float* __restrict__ W34, const float* __restrict__ b34,
        const float* __restrict__ wd2, const float* __restrict__ bd2,
        float* __restrict__ out) {
    __shared__ __align__(16) unsigned short hbuf[128 * 256];   // 64 KB

    const int w = blockIdx.x, b = w >> 7;
    const int t = threadIdx.x, wv = t >> 6, lane = t & 63;
    const int l31 = lane & 31, h5 = lane >> 5;
    const int n0 = wv * 64;

    const unsigned short* aptr = wt + lane * 8;   // + ((l*8 + wv*2+tn)*16 + kb)*512

    short8 af[2][2], bfr[2][4];
    af[0][0] = *(const short8*)(aptr + ((wv * 2 + 0) * 16) * 512);
    af[0][1] = *(const short8*)(aptr + ((wv * 2 + 1) * 16) * 512);

    // preamble: h0[j][k] = relu(ea[w][k] + eb[b*128+j][k]); wave fills j=wv*32..+31
    {
        const float4v va = *(const float4v*)(ea + w * 256 + lane * 4);
        const float* ebbase = eb + (b * NOBJ) * 256;
        const int c = lane >> 1, sub = (lane & 1) * 4;
#pragma unroll 4
        for (int jj = 0; jj < 32; ++jj) {
            const int j = wv * 32 + jj;
            float4v vb = *(const float4v*)(ebbase + j * 256 + lane * 4);
            int addr = j * 256 + ((c ^ (j & 31)) << 3) + sub;
            *(uint2v*)(hbuf + addr) = (uint2v){
                pack2(relu(va[0] + vb[0]), relu(va[1] + vb[1])),
                pack2(relu(va[2] + vb[2]), relu(va[3] + vb[3]))};
        }
    }
    lds_barrier();

    int jb[4];
#pragma unroll
    for (int tj = 0; tj < 4; ++tj) jb[tj] = (tj * 32 + l31) * 256;
#pragma unroll
    for (int tj = 0; tj < 4; ++tj)
        bfr[0][tj] = *(const short8*)(hbuf + jb[tj] + ((h5 ^ l31) << 3));

    float16v acc[2][4];   // [tn][tj]

#pragma unroll
    for (int l = 0; l < 2; ++l) {
        const float* bias = (l == 0) ? b1 : b2;
#pragma unroll
        for (int tn = 0; tn < 2; ++tn)
#pragma unroll
            for (int q = 0; q < 4; ++q) {
                float4v bv = *(const float4v*)(bias + n0 + tn * 32 + q * 8 + h5 * 4);
#pragma unroll
                for (int i = 0; i < 4; ++i)
#pragma unroll
                    for (int tj = 0; tj < 4; ++tj)
                        acc[tn][tj][q * 4 + i] = bv[i];
            }
#pragma unroll
        for (int kb = 0; kb < 16; ++kb) {
            const int g = l * 16 + kb, gp = g + 1;
            if (gp < 32) {   // prefetch next step's A (crosses the layer boundary)
                const int lp = gp >> 4, kp = gp & 15;
                af[gp & 1][0] = *(const short8*)(aptr + ((lp * 8 + wv * 2 + 0) * 16 + kp) * 512);
                af[gp & 1][1] = *(const short8*)(aptr + ((lp * 8 + wv * 2 + 1) * 16 + kp) * 512);
            }
            if (kb < 15) {   // prefetch next step's B from LDS
                const int off = ((((kb + 1) * 2 + h5) ^ l31) << 3);
#pragma unroll
                for (int tj = 0; tj < 4; ++tj)
                    bfr[(kb + 1) & 1][tj] = *(const short8*)(hbuf + jb[tj] + off);
            }
#pragma unroll
            for (int tn = 0; tn < 2; ++tn)
#pragma unroll
                for (int tj = 0; tj < 4; ++tj)
                    acc[tn][tj] = __builtin_amdgcn_mfma_f32_32x32x16_bf16(
                        af[g & 1][tn], bfr[kb & 1][tj], acc[tn][tj], 0, 0, 0);
        }
        lds_barrier();   // hbuf reads of layer l done

        if (l == 0) {
            // writeback h1 (relu, bf16) into swizzled layout
#pragma unroll
            for (int tn = 0; tn < 2; ++tn)
#pragma unroll
                for (int q = 0; q < 4; ++q) {
                    const int nb_ = n0 + tn * 32 + 8 * q + 4 * h5;
                    const int cn = nb_ >> 3, sub = nb_ & 7;
#pragma unroll
                    for (int tj = 0; tj < 4; ++tj) {
                        const int j = tj * 32 + l31;
                        int addr = j * 256 + ((cn ^ l31) << 3) + sub;
                        *(uint2v*)(hbuf + addr) = (uint2v){
                            pack2(relu(acc[tn][tj][q * 4]), relu(acc[tn][tj][q * 4 + 1])),
                            pack2(relu(acc[tn][tj][q * 4 + 2]), relu(acc[tn][tj][q * 4 + 3]))};
                    }
                }
            lds_barrier();
#pragma unroll
            for (int tj = 0; tj < 4; ++tj)
                bfr[0][tj] = *(const short8*)(hbuf + jb[tj] + ((h5 ^ l31) << 3));
        }
    }

    // ---- epilogue: m2 = mean_j relu(acc); t1 = relu(m2@W34 + b34);
    //      out = t1@wd2 + bd2. LDS regions: m2[0,256) | t1[256,512) | p2[512,768).
    float* fs = (float*)hbuf;
    {
#pragma unroll
        for (int tn = 0; tn < 2; ++tn)
#pragma unroll
            for (int r = 0; r < 16; ++r) {
                float s = relu(acc[tn][0][r]) + relu(acc[tn][1][r])
                        + relu(acc[tn][2][r]) + relu(acc[tn][3][r]);
                s += __shfl_xor(s, 1);
                s += __shfl_xor(s, 2);
                s += __shfl_xor(s, 4);
                s += __shfl_xor(s, 8);
                s += __shfl_xor(s, 16);
                if (l31 == 0) {
                    const int n = n0 + tn * 32 + (r & 3) + 8 * (r >> 2) + 4 * h5;
                    fs[n] = s * 0.0078125f;
                }
            }
    }
    __syncthreads();
    // stage 1 (direct): t1[t] = relu(sum_k m2[k]*W34[k][t] + b34[t]).
    // Reads fs[0,256), writes fs[256,512) — disjoint, no barrier in between.
    {
        float a1 = b34[t];
#pragma unroll 8
        for (int k = 0; k < 256; ++k) a1 += fs[k] * W34[k * 256 + t];
        fs[256 + t] = relu(a1);
    }
    __syncthreads();
    // stage 2: t1 @ wd2, 4-way k-split (wave wv covers k in [wv*64, +64), lane = o)
    {
        float p = 0.f;
        const float* w2p = wd2 + (wv * 64) * 64 + lane;
#pragma unroll 8
        for (int kk = 0; kk < 64; ++kk) p += fs[256 + wv * 64 + kk] * w2p[kk * 64];
        fs[512 + wv * 64 + lane] = p;
    }
    __syncthreads();
    if (t < 64)
        out[w * 64 + t] = fs[512 + t] + fs[576 + t] + fs[640 + t] + fs[704 + t] + bd2[t];
}

extern "C" void kernel_launch(void* const* d_in, const int* in_sizes, int n_in,
                              void* d_out, int out_size, void* d_ws, size_t ws_size,
                              hipStream_t stream) {
    const float* x0    = (const float*)d_in[0];
    const float* x1    = (const float*)d_in[1];
    const float* x2    = (const float*)d_in[2];
    const float* w_enc = (const float*)d_in[3];
    const float* b_enc = (const float*)d_in[4];
    const float* w1    = (const float*)d_in[5];
    const float* b1    = (const float*)d_in[6];
    const float* w2    = (const float*)d_in[7];
    const float* b2    = (const float*)d_in[8];
    const float* w3    = (const float*)d_in[9];
    const float* b3    = (const float*)d_in[10];
    const float* wd1   = (const float*)d_in[11];
    const float* bd1   = (const float*)d_in[12];
    const float* wd2   = (const float*)d_in[13];
    const float* bd2   = (const float*)d_in[14];
    float* out = (float*)d_out;

    // workspace: wfrag 256KB (384KB slot) | ea 1MB | eb 1MB | W34 256KB | b34 1KB
    unsigned short* wt = (unsigned short*)d_ws;
    float* ea  = (float*)((char*)d_ws + 3 * 65536 * sizeof(unsigned short));
    float* eb  = ea + NROW * HID;
    float* W34 = eb + NROW * HID;
    float* b34 = W34 + 256 * 256;

    setup_kernel<<<785, 256, 0, stream>>>(x0, x1, x2, w_enc, b_enc, w1, w2,
                                          w3, b3, wd1, bd1, wt, ea, eb, W34, b34);
    pair_kernel<<<NROW, 256, 0, stream>>>(ea, eb, wt, b1, b2, W34, b34, wd2, bd2, out);
}

// Round 20
// 156.532 us; speedup vs baseline: 3.4418x; 1.0317x over previous
//
#include <hip/hip_runtime.h>
#include <stdint.h>

// B=8, OBJ=128, INP=64, HID=256, D=192.
// R20 = exact restore of R16 (measured best: 154.3us total, pair 66.4us).
// Summary of what this kernel embodies (18 measured rounds):
//  - algebraic fold: mean commutes with linear fc3; w3@wd1 precomputed (W34)
//    -> only 2 of 3 MFMA layers remain (34.3 GF), h2 stays fp32 thru mean.
//  - weights packed FRAGMENT-MAJOR at setup -> A-frag loads are wave-uniform
//    base + lane*16B coalesced bursts (R10: fixed the L2 request-rate wall).
//  - wave tile n=64 x j=128 (tn=2 x tj=4, 32x32x16 MFMA), af ring-2 dist-1,
//    row-major XOR-swizzled LDS h-buffer (R13/R14/R19 alternatives all
//    regressed), lgkm-only barriers keep global prefetch in flight.
//  - decoder fused into the pair epilogue (R13: saves a ~30us boundary);
//    4-way k-split GEMVs (R19's direct chain was slower).
//  - single-launch fusion rejected: coop launch unsupported (R17), software
//    spin barrier costs ~400us in coherence traffic (R18).

#define HID 256
#define NOBJ 128
#define NROW 1024   // B*OBJ

typedef __attribute__((ext_vector_type(8))) short short8;
typedef __attribute__((ext_vector_type(4))) float float4v;
typedef __attribute__((ext_vector_type(16))) float float16v;
typedef __attribute__((ext_vector_type(2))) unsigned int uint2v;

__device__ __forceinline__ unsigned int f2bf_u(float f) {
    unsigned int u = __builtin_bit_cast(unsigned int, f);
    u += 0x7fffu + ((u >> 16) & 1u);   // RNE
    return u >> 16;
}
__device__ __forceinline__ unsigned int pack2(float a, float b) {
    return f2bf_u(a) | (f2bf_u(b) << 16);
}
__device__ __forceinline__ float relu(float v) { return v > 0.f ? v : 0.f; }

// LDS-only barrier: leaves global-load (vmcnt) prefetches in flight.
__device__ __forceinline__ void lds_barrier() {
    asm volatile("s_waitcnt lgkmcnt(0)\n\ts_barrier" ::: "memory");
}

// ---- setup:
//  blocks [0,16): fragment-major pack of w1,w2 (layer m = bx>>3, n-tile tau = bx&7)
//  blocks [16,528): encoder, 2 rows each (fold b_enc into ea)
//  blocks [528,784): W34 row m = bx-528:  W34[m][o] = sum_k w3[m][k]*wd1[k][o]
//  block  784:       b34[o] = sum_k b3[k]*wd1[k][o] + bd1[o]
__global__ void setup_kernel(const float* __restrict__ x0, const float* __restrict__ x1,
                             const float* __restrict__ x2, const float* __restrict__ w_enc,
                             const float* __restrict__ b_enc,
                             const float* __restrict__ w1, const float* __restrict__ w2,
                             const float* __restrict__ w3, const float* __restrict__ b3,
                             const float* __restrict__ wd1, const float* __restrict__ bd1,
                             unsigned short* __restrict__ wt,
                             float* __restrict__ ea, float* __restrict__ eb,
                             float* __restrict__ W34, float* __restrict__ b34) {
    const int bx = blockIdx.x, t = threadIdx.x;
    __shared__ float lw[256][33];          // [k][n-within-tile]
    __shared__ float xs[2][192];
    if (bx < 16) {
        const int m = bx >> 3, tau = bx & 7;
        const float* w = (m == 0) ? w1 : w2;
        const int n = t & 31, kk = t >> 5;     // 8 k-rows per pass
#pragma unroll
        for (int rep = 0; rep < 32; ++rep) {
            int k = rep * 8 + kk;
            lw[k][n] = w[k * 256 + tau * 32 + n];   // coalesced 128B segments
        }
        __syncthreads();
        unsigned short* outp = wt + (m * 8 + tau) * 8192;
        const int lane = t & 63, wq = t >> 6;
        const int h5 = lane >> 5, l31n = lane & 31;
#pragma unroll
        for (int rep = 0; rep < 4; ++rep) {
            const int kb = wq * 4 + rep;
            short8 v;
#pragma unroll
            for (int e = 0; e < 8; ++e)
                v[e] = (short)f2bf_u(lw[kb * 16 + h5 * 8 + e][l31n]);
            *(short8*)(outp + kb * 512 + lane * 8) = v;   // wave-contiguous 1KB
        }
        return;
    }
    if (bx < 528) {
        const int e = bx - 16;                 // 512 groups x 2 rows
        for (int idx = t; idx < 384; idx += 256) {
            int r = idx / 192, d = idx % 192;
            int row = e * 2 + r;
            float v = (d < 64) ? x0[row * 64 + d]
                    : (d < 128) ? x1[row * 64 + d - 64]
                    : x2[row * 64 + d - 128];
            xs[r][d] = v;
        }
        __syncthreads();
        float aA[2] = {0.f, 0.f}, aB[2] = {0.f, 0.f};
#pragma unroll 16
        for (int d = 0; d < 192; ++d) {
            float wa = w_enc[d * 256 + t];
            float wb = w_enc[(192 + d) * 256 + t];
#pragma unroll
            for (int r = 0; r < 2; ++r) { aA[r] += xs[r][d] * wa; aB[r] += xs[r][d] * wb; }
        }
        float be = b_enc[t];
#pragma unroll
        for (int r = 0; r < 2; ++r) {
            ea[(e * 2 + r) * 256 + t] = aA[r] + be;
            eb[(e * 2 + r) * 256 + t] = aB[r];
        }
        return;
    }
    if (bx < 784) {
        const int m = bx - 528;
        float a = 0.f;
#pragma unroll 8
        for (int k = 0; k < 256; ++k) a += w3[m * 256 + k] * wd1[k * 256 + t];
        W34[m * 256 + t] = a;
        return;
    }
    {   // b34
        float a = bd1[t];
#pragma unroll 8
        for (int k = 0; k < 256; ++k) a += b3[k] * wd1[k * 256 + t];
        b34[t] = a;
    }
}

// ---- pair MLP (2 layers) + fused decoder: grid 1024, one WG per (b,i).
//      128 j-rows, 64 KB LDS h, swizzle: elem(j,k) at
//      j*256 + ((k>>3 ^ (j&31))<<3) + (k&7). Wave wv owns n-quarter n0=wv*64
//      as tn=2 x tj=4 tiles of 32x32x16. af ring-2 (distance 1).
__global__ __launch_bounds__(256, 2) void pair_kernel(
        const float* __restrict__ ea, const float* __restrict__ eb,
        const unsigned short* __restrict__ wt,
        const float* __restrict__ b1, const float* __restrict__ b2,
        const float* __restrict__ W34, const float* __restrict__ b34,
        const float* __restrict__ wd2, const float* __restrict__ bd2,
        float* __restrict__ out) {
    __shared__ __align__(16) unsigned short hbuf[128 * 256];   // 64 KB

    const int w = blockIdx.x, b = w >> 7;
    const int t = threadIdx.x, wv = t >> 6, lane = t & 63;
    const int l31 = lane & 31, h5 = lane >> 5;
    const int n0 = wv * 64;

    const unsigned short* aptr = wt + lane * 8;   // + ((l*8 + wv*2+tn)*16 + kb)*512

    short8 af[2][2], bfr[2][4];
    af[0][0] = *(const short8*)(aptr + ((wv * 2 + 0) * 16) * 512);
    af[0][1] = *(const short8*)(aptr + ((wv * 2 + 1) * 16) * 512);

    // preamble: h0[j][k] = relu(ea[w][k] + eb[b*128+j][k]); wave fills j=wv*32..+31
    {
        const float4v va = *(const float4v*)(ea + w * 256 + lane * 4);
        const float* ebbase = eb + (b * NOBJ) * 256;
        const int c = lane >> 1, sub = (lane & 1) * 4;
#pragma unroll 4
        for (int jj = 0; jj < 32; ++jj) {
            const int j = wv * 32 + jj;
            float4v vb = *(const float4v*)(ebbase + j * 256 + lane * 4);
            int addr = j * 256 + ((c ^ (j & 31)) << 3) + sub;
            *(uint2v*)(hbuf + addr) = (uint2v){
                pack2(relu(va[0] + vb[0]), relu(va[1] + vb[1])),
                pack2(relu(va[2] + vb[2]), relu(va[3] + vb[3]))};
        }
    }
    lds_barrier();

    int jb[4];
#pragma unroll
    for (int tj = 0; tj < 4; ++tj) jb[tj] = (tj * 32 + l31) * 256;
#pragma unroll
    for (int tj = 0; tj < 4; ++tj)
        bfr[0][tj] = *(const short8*)(hbuf + jb[tj] + ((h5 ^ l31) << 3));

    float16v acc[2][4];   // [tn][tj]

#pragma unroll
    for (int l = 0; l < 2; ++l) {
        const float* bias = (l == 0) ? b1 : b2;
#pragma unroll
        for (int tn = 0; tn < 2; ++tn)
#pragma unroll
            for (int q = 0; q < 4; ++q) {
                float4v bv = *(const float4v*)(bias + n0 + tn * 32 + q * 8 + h5 * 4);
#pragma unroll
                for (int i = 0; i < 4; ++i)
#pragma unroll
                    for (int tj = 0; tj < 4; ++tj)
                        acc[tn][tj][q * 4 + i] = bv[i];
            }
#pragma unroll
        for (int kb = 0; kb < 16; ++kb) {
            const int g = l * 16 + kb, gp = g + 1;
            if (gp < 32) {   // prefetch next step's A (crosses the layer boundary)
                const int lp = gp >> 4, kp = gp & 15;
                af[gp & 1][0] = *(const short8*)(aptr + ((lp * 8 + wv * 2 + 0) * 16 + kp) * 512);
                af[gp & 1][1] = *(const short8*)(aptr + ((lp * 8 + wv * 2 + 1) * 16 + kp) * 512);
            }
            if (kb < 15) {   // prefetch next step's B from LDS
                const int off = ((((kb + 1) * 2 + h5) ^ l31) << 3);
#pragma unroll
                for (int tj = 0; tj < 4; ++tj)
                    bfr[(kb + 1) & 1][tj] = *(const short8*)(hbuf + jb[tj] + off);
            }
#pragma unroll
            for (int tn = 0; tn < 2; ++tn)
#pragma unroll
                for (int tj = 0; tj < 4; ++tj)
                    acc[tn][tj] = __builtin_amdgcn_mfma_f32_32x32x16_bf16(
                        af[g & 1][tn], bfr[kb & 1][tj], acc[tn][tj], 0, 0, 0);
        }
        lds_barrier();   // hbuf reads of layer l done

        if (l == 0) {
            // writeback h1 (relu, bf16) into swizzled layout
#pragma unroll
            for (int tn = 0; tn < 2; ++tn)
#pragma unroll
                for (int q = 0; q < 4; ++q) {
                    const int nb_ = n0 + tn * 32 + 8 * q + 4 * h5;
                    const int cn = nb_ >> 3, sub = nb_ & 7;
#pragma unroll
                    for (int tj = 0; tj < 4; ++tj) {
                        const int j = tj * 32 + l31;
                        int addr = j * 256 + ((cn ^ l31) << 3) + sub;
                        *(uint2v*)(hbuf + addr) = (uint2v){
                            pack2(relu(acc[tn][tj][q * 4]), relu(acc[tn][tj][q * 4 + 1])),
                            pack2(relu(acc[tn][tj][q * 4 + 2]), relu(acc[tn][tj][q * 4 + 3]))};
                    }
                }
            lds_barrier();
#pragma unroll
            for (int tj = 0; tj < 4; ++tj)
                bfr[0][tj] = *(const short8*)(hbuf + jb[tj] + ((h5 ^ l31) << 3));
        }
    }

    // ---- epilogue: m2 = mean_j relu(acc); t1 = relu(m2@W34 + b34); out = t1@wd2+bd2
    float* fs = (float*)hbuf;   // m2[0..256) | p1[256..1280) | t1[1280..1536) | p2[1536..1792)
    {
#pragma unroll
        for (int tn = 0; tn < 2; ++tn)
#pragma unroll
            for (int r = 0; r < 16; ++r) {
                float s = relu(acc[tn][0][r]) + relu(acc[tn][1][r])
                        + relu(acc[tn][2][r]) + relu(acc[tn][3][r]);
                s += __shfl_xor(s, 1);
                s += __shfl_xor(s, 2);
                s += __shfl_xor(s, 4);
                s += __shfl_xor(s, 8);
                s += __shfl_xor(s, 16);
                if (l31 == 0) {
                    const int n = n0 + tn * 32 + (r & 3) + 8 * (r >> 2) + 4 * h5;
                    fs[n] = s * 0.0078125f;
                }
            }
    }
    __syncthreads();
    // stage 1: m2 @ W34 with 4-way k-split (wave wv covers k in [wv*64, wv*64+64))
    {
        float p0 = 0.f, p1 = 0.f, p2 = 0.f, p3 = 0.f;
        const float* wp = W34 + (wv * 64) * 256 + lane;
#pragma unroll 8
        for (int kk = 0; kk < 64; ++kk) {
            float mv = fs[wv * 64 + kk];
            p0 += mv * wp[kk * 256];
            p1 += mv * wp[kk * 256 + 64];
            p2 += mv * wp[kk * 256 + 128];
            p3 += mv * wp[kk * 256 + 192];
        }
        fs[256 + wv * 256 + lane]       = p0;
        fs[256 + wv * 256 + 64 + lane]  = p1;
        fs[256 + wv * 256 + 128 + lane] = p2;
        fs[256 + wv * 256 + 192 + lane] = p3;
    }
    __syncthreads();
    fs[1280 + t] = relu(fs[256 + t] + fs[512 + t] + fs[768 + t] + fs[1024 + t] + b34[t]);
    __syncthreads();
    // stage 2: t1 @ wd2 (wave wv covers k in [wv*64, wv*64+64), lane = output o)
    {
        float p = 0.f;
        const float* w2p = wd2 + (wv * 64) * 64 + lane;
#pragma unroll 8
        for (int kk = 0; kk < 64; ++kk) p += fs[1280 + wv * 64 + kk] * w2p[kk * 64];
        fs[1536 + wv * 64 + lane] = p;
    }
    __syncthreads();
    if (t < 64)
        out[w * 64 + t] = fs[1536 + t] + fs[1600 + t] + fs[1664 + t] + fs[1728 + t] + bd2[t];
}

extern "C" void kernel_launch(void* const* d_in, const int* in_sizes, int n_in,
                              void* d_out, int out_size, void* d_ws, size_t ws_size,
                              hipStream_t stream) {
    const float* x0    = (const float*)d_in[0];
    const float* x1    = (const float*)d_in[1];
    const float* x2    = (const float*)d_in[2];
    const float* w_enc = (const float*)d_in[3];
    const float* b_enc = (const float*)d_in[4];
    const float* w1    = (const float*)d_in[5];
    const float* b1    = (const float*)d_in[6];
    const float* w2    = (const float*)d_in[7];
    const float* b2    = (const float*)d_in[8];
    const float* w3    = (const float*)d_in[9];
    const float* b3    = (const float*)d_in[10];
    const float* wd1   = (const float*)d_in[11];
    const float* bd1   = (const float*)d_in[12];
    const float* wd2   = (const float*)d_in[13];
    const float* bd2   = (const float*)d_in[14];
    float* out = (float*)d_out;

    // workspace: wfrag 256KB (in 384KB slot) | ea 1MB | eb 1MB | W34 256KB | b34 1KB
    unsigned short* wt = (unsigned short*)d_ws;
    float* ea  = (float*)((char*)d_ws + 3 * 65536 * sizeof(unsigned short));
    float* eb  = ea + NROW * HID;
    float* W34 = eb + NROW * HID;
    float* b34 = W34 + 256 * 256;

    setup_kernel<<<785, 256, 0, stream>>>(x0, x1, x2, w_enc, b_enc, w1, w2,
                                          w3, b3, wd1, bd1, wt, ea, eb, W34, b34);
    pair_kernel<<<NROW, 256, 0, stream>>>(ea, eb, wt, b1, b2, W34, b34, wd2, bd2, out);
}

// Round 21
// 153.713 us; speedup vs baseline: 3.5049x; 1.0183x over previous
//
#include <hip/hip_runtime.h>
#include <stdint.h>

// B=8, OBJ=128, INP=64, HID=256, D=192.
// R21 = R20 (= R16, best stable 154-157us) with ONE change: af prefetch
// ring-4 (distance 3). Basis: the only controlled ring A/B with the fused
// epilogue (R13 ring-4 82.6us vs R15 ring-2 86.2us, all else equal) favors
// ring-4 by ~4%; R16 reverted to ring-2 on a misattributed comparison.
// Everything else byte-identical to R20.

#define HID 256
#define NOBJ 128
#define NROW 1024   // B*OBJ

typedef __attribute__((ext_vector_type(8))) short short8;
typedef __attribute__((ext_vector_type(4))) float float4v;
typedef __attribute__((ext_vector_type(16))) float float16v;
typedef __attribute__((ext_vector_type(2))) unsigned int uint2v;

__device__ __forceinline__ unsigned int f2bf_u(float f) {
    unsigned int u = __builtin_bit_cast(unsigned int, f);
    u += 0x7fffu + ((u >> 16) & 1u);   // RNE
    return u >> 16;
}
__device__ __forceinline__ unsigned int pack2(float a, float b) {
    return f2bf_u(a) | (f2bf_u(b) << 16);
}
__device__ __forceinline__ float relu(float v) { return v > 0.f ? v : 0.f; }

// LDS-only barrier: leaves global-load (vmcnt) prefetches in flight.
__device__ __forceinline__ void lds_barrier() {
    asm volatile("s_waitcnt lgkmcnt(0)\n\ts_barrier" ::: "memory");
}

// ---- setup:
//  blocks [0,16): fragment-major pack of w1,w2 (layer m = bx>>3, n-tile tau = bx&7)
//  blocks [16,528): encoder, 2 rows each (fold b_enc into ea)
//  blocks [528,784): W34 row m = bx-528:  W34[m][o] = sum_k w3[m][k]*wd1[k][o]
//  block  784:       b34[o] = sum_k b3[k]*wd1[k][o] + bd1[o]
__global__ void setup_kernel(const float* __restrict__ x0, const float* __restrict__ x1,
                             const float* __restrict__ x2, const float* __restrict__ w_enc,
                             const float* __restrict__ b_enc,
                             const float* __restrict__ w1, const float* __restrict__ w2,
                             const float* __restrict__ w3, const float* __restrict__ b3,
                             const float* __restrict__ wd1, const float* __restrict__ bd1,
                             unsigned short* __restrict__ wt,
                             float* __restrict__ ea, float* __restrict__ eb,
                             float* __restrict__ W34, float* __restrict__ b34) {
    const int bx = blockIdx.x, t = threadIdx.x;
    __shared__ float lw[256][33];          // [k][n-within-tile]
    __shared__ float xs[2][192];
    if (bx < 16) {
        const int m = bx >> 3, tau = bx & 7;
        const float* w = (m == 0) ? w1 : w2;
        const int n = t & 31, kk = t >> 5;     // 8 k-rows per pass
#pragma unroll
        for (int rep = 0; rep < 32; ++rep) {
            int k = rep * 8 + kk;
            lw[k][n] = w[k * 256 + tau * 32 + n];   // coalesced 128B segments
        }
        __syncthreads();
        unsigned short* outp = wt + (m * 8 + tau) * 8192;
        const int lane = t & 63, wq = t >> 6;
        const int h5 = lane >> 5, l31n = lane & 31;
#pragma unroll
        for (int rep = 0; rep < 4; ++rep) {
            const int kb = wq * 4 + rep;
            short8 v;
#pragma unroll
            for (int e = 0; e < 8; ++e)
                v[e] = (short)f2bf_u(lw[kb * 16 + h5 * 8 + e][l31n]);
            *(short8*)(outp + kb * 512 + lane * 8) = v;   // wave-contiguous 1KB
        }
        return;
    }
    if (bx < 528) {
        const int e = bx - 16;                 // 512 groups x 2 rows
        for (int idx = t; idx < 384; idx += 256) {
            int r = idx / 192, d = idx % 192;
            int row = e * 2 + r;
            float v = (d < 64) ? x0[row * 64 + d]
                    : (d < 128) ? x1[row * 64 + d - 64]
                    : x2[row * 64 + d - 128];
            xs[r][d] = v;
        }
        __syncthreads();
        float aA[2] = {0.f, 0.f}, aB[2] = {0.f, 0.f};
#pragma unroll 16
        for (int d = 0; d < 192; ++d) {
            float wa = w_enc[d * 256 + t];
            float wb = w_enc[(192 + d) * 256 + t];
#pragma unroll
            for (int r = 0; r < 2; ++r) { aA[r] += xs[r][d] * wa; aB[r] += xs[r][d] * wb; }
        }
        float be = b_enc[t];
#pragma unroll
        for (int r = 0; r < 2; ++r) {
            ea[(e * 2 + r) * 256 + t] = aA[r] + be;
            eb[(e * 2 + r) * 256 + t] = aB[r];
        }
        return;
    }
    if (bx < 784) {
        const int m = bx - 528;
        float a = 0.f;
#pragma unroll 8
        for (int k = 0; k < 256; ++k) a += w3[m * 256 + k] * wd1[k * 256 + t];
        W34[m * 256 + t] = a;
        return;
    }
    {   // b34
        float a = bd1[t];
#pragma unroll 8
        for (int k = 0; k < 256; ++k) a += b3[k] * wd1[k * 256 + t];
        b34[t] = a;
    }
}

// ---- pair MLP (2 layers) + fused decoder: grid 1024, one WG per (b,i).
//      128 j-rows, 64 KB LDS h, swizzle: elem(j,k) at
//      j*256 + ((k>>3 ^ (j&31))<<3) + (k&7). Wave wv owns n-quarter n0=wv*64
//      as tn=2 x tj=4 tiles of 32x32x16. af ring-4 (prefetch distance 3).
__global__ __launch_bounds__(256, 2) void pair_kernel(
        const float* __restrict__ ea, const float* __restrict__ eb,
        const unsigned short* __restrict__ wt,
        const float* __restrict__ b1, const float* __restrict__ b2,
        const float* __restrict__ W34, const float* __restrict__ b34,
        const float* __restrict__ wd2, const float* __restrict__ bd2,
        float* __restrict__ out) {
    __shared__ __align__(16) unsigned short hbuf[128 * 256];   // 64 KB

    const int w = blockIdx.x, b = w >> 7;
    const int t = threadIdx.x, wv = t >> 6, lane = t & 63;
    const int l31 = lane & 31, h5 = lane >> 5;
    const int n0 = wv * 64;

    const unsigned short* aptr = wt + lane * 8;   // + ((l*8 + wv*2+tn)*16 + kb)*512

    short8 af[4][2], bfr[2][4];
    // ring-4 preload: steps g = 0,1,2 of layer 0
#pragma unroll
    for (int pg = 0; pg < 3; ++pg) {
        af[pg][0] = *(const short8*)(aptr + ((wv * 2 + 0) * 16 + pg) * 512);
        af[pg][1] = *(const short8*)(aptr + ((wv * 2 + 1) * 16 + pg) * 512);
    }

    // preamble: h0[j][k] = relu(ea[w][k] + eb[b*128+j][k]); wave fills j=wv*32..+31
    {
        const float4v va = *(const float4v*)(ea + w * 256 + lane * 4);
        const float* ebbase = eb + (b * NOBJ) * 256;
        const int c = lane >> 1, sub = (lane & 1) * 4;
#pragma unroll 4
        for (int jj = 0; jj < 32; ++jj) {
            const int j = wv * 32 + jj;
            float4v vb = *(const float4v*)(ebbase + j * 256 + lane * 4);
            int addr = j * 256 + ((c ^ (j & 31)) << 3) + sub;
            *(uint2v*)(hbuf + addr) = (uint2v){
                pack2(relu(va[0] + vb[0]), relu(va[1] + vb[1])),
                pack2(relu(va[2] + vb[2]), relu(va[3] + vb[3]))};
        }
    }
    lds_barrier();

    int jb[4];
#pragma unroll
    for (int tj = 0; tj < 4; ++tj) jb[tj] = (tj * 32 + l31) * 256;
#pragma unroll
    for (int tj = 0; tj < 4; ++tj)
        bfr[0][tj] = *(const short8*)(hbuf + jb[tj] + ((h5 ^ l31) << 3));

    float16v acc[2][4];   // [tn][tj]

#pragma unroll
    for (int l = 0; l < 2; ++l) {
        const float* bias = (l == 0) ? b1 : b2;
#pragma unroll
        for (int tn = 0; tn < 2; ++tn)
#pragma unroll
            for (int q = 0; q < 4; ++q) {
                float4v bv = *(const float4v*)(bias + n0 + tn * 32 + q * 8 + h5 * 4);
#pragma unroll
                for (int i = 0; i < 4; ++i)
#pragma unroll
                    for (int tj = 0; tj < 4; ++tj)
                        acc[tn][tj][q * 4 + i] = bv[i];
            }
#pragma unroll
        for (int kb = 0; kb < 16; ++kb) {
            const int g = l * 16 + kb, gp = g + 3;
            if (gp < 32) {   // prefetch 3 steps ahead (crosses the layer boundary)
                const int lp = gp >> 4, kp = gp & 15;
                af[gp & 3][0] = *(const short8*)(aptr + ((lp * 8 + wv * 2 + 0) * 16 + kp) * 512);
                af[gp & 3][1] = *(const short8*)(aptr + ((lp * 8 + wv * 2 + 1) * 16 + kp) * 512);
            }
            if (kb < 15) {   // prefetch next step's B from LDS
                const int off = ((((kb + 1) * 2 + h5) ^ l31) << 3);
#pragma unroll
                for (int tj = 0; tj < 4; ++tj)
                    bfr[(kb + 1) & 1][tj] = *(const short8*)(hbuf + jb[tj] + off);
            }
#pragma unroll
            for (int tn = 0; tn < 2; ++tn)
#pragma unroll
                for (int tj = 0; tj < 4; ++tj)
                    acc[tn][tj] = __builtin_amdgcn_mfma_f32_32x32x16_bf16(
                        af[g & 3][tn], bfr[kb & 1][tj], acc[tn][tj], 0, 0, 0);
        }
        lds_barrier();   // hbuf reads of layer l done

        if (l == 0) {
            // writeback h1 (relu, bf16) into swizzled layout
#pragma unroll
            for (int tn = 0; tn < 2; ++tn)
#pragma unroll
                for (int q = 0; q < 4; ++q) {
                    const int nb_ = n0 + tn * 32 + 8 * q + 4 * h5;
                    const int cn = nb_ >> 3, sub = nb_ & 7;
#pragma unroll
                    for (int tj = 0; tj < 4; ++tj) {
                        const int j = tj * 32 + l31;
                        int addr = j * 256 + ((cn ^ l31) << 3) + sub;
                        *(uint2v*)(hbuf + addr) = (uint2v){
                            pack2(relu(acc[tn][tj][q * 4]), relu(acc[tn][tj][q * 4 + 1])),
                            pack2(relu(acc[tn][tj][q * 4 + 2]), relu(acc[tn][tj][q * 4 + 3]))};
                    }
                }
            lds_barrier();
#pragma unroll
            for (int tj = 0; tj < 4; ++tj)
                bfr[0][tj] = *(const short8*)(hbuf + jb[tj] + ((h5 ^ l31) << 3));
        }
    }

    // ---- epilogue: m2 = mean_j relu(acc); t1 = relu(m2@W34 + b34); out = t1@wd2+bd2
    float* fs = (float*)hbuf;   // m2[0..256) | p1[256..1280) | t1[1280..1536) | p2[1536..1792)
    {
#pragma unroll
        for (int tn = 0; tn < 2; ++tn)
#pragma unroll
            for (int r = 0; r < 16; ++r) {
                float s = relu(acc[tn][0][r]) + relu(acc[tn][1][r])
                        + relu(acc[tn][2][r]) + relu(acc[tn][3][r]);
                s += __shfl_xor(s, 1);
                s += __shfl_xor(s, 2);
                s += __shfl_xor(s, 4);
                s += __shfl_xor(s, 8);
                s += __shfl_xor(s, 16);
                if (l31 == 0) {
                    const int n = n0 + tn * 32 + (r & 3) + 8 * (r >> 2) + 4 * h5;
                    fs[n] = s * 0.0078125f;
                }
            }
    }
    __syncthreads();
    // stage 1: m2 @ W34 with 4-way k-split (wave wv covers k in [wv*64, wv*64+64))
    {
        float p0 = 0.f, p1 = 0.f, p2 = 0.f, p3 = 0.f;
        const float* wp = W34 + (wv * 64) * 256 + lane;
#pragma unroll 8
        for (int kk = 0; kk < 64; ++kk) {
            float mv = fs[wv * 64 + kk];
            p0 += mv * wp[kk * 256];
            p1 += mv * wp[kk * 256 + 64];
            p2 += mv * wp[kk * 256 + 128];
            p3 += mv * wp[kk * 256 + 192];
        }
        fs[256 + wv * 256 + lane]       = p0;
        fs[256 + wv * 256 + 64 + lane]  = p1;
        fs[256 + wv * 256 + 128 + lane] = p2;
        fs[256 + wv * 256 + 192 + lane] = p3;
    }
    __syncthreads();
    fs[1280 + t] = relu(fs[256 + t] + fs[512 + t] + fs[768 + t] + fs[1024 + t] + b34[t]);
    __syncthreads();
    // stage 2: t1 @ wd2 (wave wv covers k in [wv*64, wv*64+64), lane = output o)
    {
        float p = 0.f;
        const float* w2p = wd2 + (wv * 64) * 64 + lane;
#pragma unroll 8
        for (int kk = 0; kk < 64; ++kk) p += fs[1280 + wv * 64 + kk] * w2p[kk * 64];
        fs[1536 + wv * 64 + lane] = p;
    }
    __syncthreads();
    if (t < 64)
        out[w * 64 + t] = fs[1536 + t] + fs[1600 + t] + fs[1664 + t] + fs[1728 + t] + bd2[t];
}

extern "C" void kernel_launch(void* const* d_in, const int* in_sizes, int n_in,
                              void* d_out, int out_size, void* d_ws, size_t ws_size,
                              hipStream_t stream) {
    const float* x0    = (const float*)d_in[0];
    const float* x1    = (const float*)d_in[1];
    const float* x2    = (const float*)d_in[2];
    const float* w_enc = (const float*)d_in[3];
    const float* b_enc = (const float*)d_in[4];
    const float* w1    = (const float*)d_in[5];
    const float* b1    = (const float*)d_in[6];
    const float* w2    = (const float*)d_in[7];
    const float* b2    = (const float*)d_in[8];
    const float* w3    = (const float*)d_in[9];
    const float* b3    = (const float*)d_in[10];
    const float* wd1   = (const float*)d_in[11];
    const float* bd1   = (const float*)d_in[12];
    const float* wd2   = (const float*)d_in[13];
    const float* bd2   = (const float*)d_in[14];
    float* out = (float*)d_out;

    // workspace: wfrag 256KB (in 384KB slot) | ea 1MB | eb 1MB | W34 256KB | b34 1KB
    unsigned short* wt = (unsigned short*)d_ws;
    float* ea  = (float*)((char*)d_ws + 3 * 65536 * sizeof(unsigned short));
    float* eb  = ea + NROW * HID;
    float* W34 = eb + NROW * HID;
    float* b34 = W34 + 256 * 256;

    setup_kernel<<<785, 256, 0, stream>>>(x0, x1, x2, w_enc, b_enc, w1, w2,
                                          w3, b3, wd1, bd1, wt, ea, eb, W34, b34);
    pair_kernel<<<NROW, 256, 0, stream>>>(ea, eb, wt, b1, b2, W34, b34, wd2, bd2, out);
}